// Round 12
// baseline (329.791 us; speedup 1.0000x reference)
//
#include <hip/hip_runtime.h>
#include <hip/hip_bf16.h>
#include <stdint.h>
#include <math.h>

#define B_ 2
#define S_ 2048
#define H_ 2048
#define NH_ 16
#define NKV_ 4
#define HD_ 128

typedef __bf16 bf16;
typedef __bf16 bf16x8 __attribute__((ext_vector_type(8)));
typedef __bf16 bf16x4 __attribute__((ext_vector_type(4)));
typedef float f32x4 __attribute__((ext_vector_type(4)));

__device__ __forceinline__ void async_copy16(const void* g, void* l) {
  __builtin_amdgcn_global_load_lds(
      (const __attribute__((address_space(1))) void*)(uintptr_t)g,
      (__attribute__((address_space(3))) void*)(uintptr_t)l,
      16, 0, 0);
}

__device__ __forceinline__ f32x4 mfma16(bf16x8 a, bf16x8 b, f32x4 c) {
  return __builtin_amdgcn_mfma_f32_16x16x32_bf16(a, b, c, 0, 0, 0);
}

// ---------------- merged prep kernel ----------------

__global__ void prep_all_k(const float* __restrict__ x,
                           const float* __restrict__ Wq, const float* __restrict__ Wk,
                           const float* __restrict__ Wv, const float* __restrict__ Wo,
                           bf16* __restrict__ xb, bf16* __restrict__ WqkvT,
                           bf16* __restrict__ WoT, float2* __restrict__ tab) {
  __shared__ float tile[32][33];
  const int bid = blockIdx.x;
  const int tid = threadIdx.x;

  if (bid < 10240) {
    const float* W; bf16* Wt; int N, bx, by;
    if (bid < 4096)      { W = Wq; Wt = WqkvT;                       N = 2048; int b2 = bid;        bx = b2 & 63; by = b2 >> 6; }
    else if (bid < 5120) { W = Wk; Wt = WqkvT + (size_t)2048 * 2048; N = 512;  int b2 = bid - 4096; bx = b2 & 15; by = b2 >> 4; }
    else if (bid < 6144) { W = Wv; Wt = WqkvT + (size_t)2560 * 2048; N = 512;  int b2 = bid - 5120; bx = b2 & 15; by = b2 >> 4; }
    else                 { W = Wo; Wt = WoT;                         N = 2048; int b2 = bid - 6144; bx = b2 & 63; by = b2 >> 6; }
    const int K = 2048;
    int n0 = bx * 32, k0 = by * 32;
    int tx = tid & 31, ty = tid >> 5;   // (32, 8)
#pragma unroll
    for (int j = 0; j < 32; j += 8)
      tile[ty + j][tx] = W[(size_t)(k0 + ty + j) * N + n0 + tx];
    __syncthreads();
#pragma unroll
    for (int j = 0; j < 32; j += 8)
      Wt[(size_t)(n0 + ty + j) * K + k0 + tx] = (bf16)tile[tx][ty + j];
  } else if (bid < 18432) {
    int i = ((bid - 10240) * 256 + tid) * 4;
    float4 v = *(const float4*)(x + i);
    bf16x4 r;
    r[0] = (bf16)v.x; r[1] = (bf16)v.y; r[2] = (bf16)v.z; r[3] = (bf16)v.w;
    *(bf16x4*)(xb + i) = r;
  } else {
    int i = (bid - 18432) * 256 + tid;   // S_*64
    int p = i >> 6, d = i & 63;
    float invf = expf(-((float)(2 * d) / 128.0f) * 9.210340371976184f);
    float fr = (float)p * invf;
    float sv, cv;
    sincosf(fr, &sv, &cv);
    tab[i] = make_float2(cv, sv);
  }
}

// merged vectorized RoPE for Q and K.
__global__ void rope_both_k(bf16* __restrict__ bq, bf16* __restrict__ bk,
                            const int* __restrict__ pos_ids,
                            const float2* __restrict__ tab) {
  int bid = blockIdx.x;
  bf16* t; int hshift, hmask, i; float scale;
  if (bid < 2048) { t = bq; hshift = 4; hmask = 15; scale = 0.12753102f; i = bid * 256 + threadIdx.x; }
  else            { t = bk; hshift = 2; hmask = 3;  scale = 1.0f;        i = (bid - 2048) * 256 + threadIdx.x; }
  int g = i & 7;
  int tmp = i >> 3;
  int h = tmp & hmask;
  int row = tmp >> hshift;
  int pos = pos_ids[row];
  size_t base = (((size_t)row << hshift) + h) * HD_ + g * 8;
  const float2* tb = tab + pos * 64 + g * 8;
  bf16x8 lo = *(const bf16x8*)(t + base);
  bf16x8 hi = *(const bf16x8*)(t + base + 64);
  float4 t0 = *(const float4*)(tb);
  float4 t1 = *(const float4*)(tb + 2);
  float4 t2 = *(const float4*)(tb + 4);
  float4 t3 = *(const float4*)(tb + 6);
  float cs[8], sn[8];
  cs[0]=t0.x; sn[0]=t0.y; cs[1]=t0.z; sn[1]=t0.w;
  cs[2]=t1.x; sn[2]=t1.y; cs[3]=t1.z; sn[3]=t1.w;
  cs[4]=t2.x; sn[4]=t2.y; cs[5]=t2.z; sn[5]=t2.w;
  cs[6]=t3.x; sn[6]=t3.y; cs[7]=t3.z; sn[7]=t3.w;
  bf16x8 olo, ohi;
#pragma unroll
  for (int j = 0; j < 8; ++j) {
    float a = (float)lo[j], b = (float)hi[j];
    olo[j] = (bf16)((a * cs[j] - b * sn[j]) * scale);
    ohi[j] = (bf16)((b * cs[j] + a * sn[j]) * scale);
  }
  *(bf16x8*)(t + base) = olo;
  *(bf16x8*)(t + base + 64) = ohi;
}

// ---------------- 256xBN 8-wave GEMM (m201-style) ----------------

template <int MODE, int NJ>
__global__ __launch_bounds__(512) void gemm256_k(const bf16* __restrict__ A,
                                                 const bf16* __restrict__ Bt,
                                                 void* __restrict__ C0,
                                                 void* __restrict__ C1,
                                                 void* __restrict__ C2,
                                                 int M, int N, int K) {
  extern __shared__ __align__(16) char smem[];
  constexpr int BUFSZ = 32768 + NJ * 8192;
  const int tid = threadIdx.x;
  const int lane = tid & 63;
  const int w = tid >> 6;
  const int wm = w >> 2;
  const int wn = w & 3;
  const int g16 = lane >> 4, c16 = lane & 15;
  const int row0 = blockIdx.y * 256;
  const int col0 = blockIdx.x * (NJ * 64);
  const int srow = tid >> 3;
  const int sslot = tid & 7;
  const int ldsw = w * 1024;

  auto stage = [&](int buf, int kt, int r) {
    int rr = (r < 4) ? r : r - 4;
    int row = rr * 64 + srow;
    int ss = sslot ^ (row & 7);
    const bf16* src = (r < 4) ? (A + (size_t)(row0 + row) * K)
                              : (Bt + (size_t)(col0 + row) * K);
    async_copy16(src + (kt << 6) + ss * 8,
                 smem + buf * BUFSZ + ((r < 4) ? 0 : 32768) + rr * 8192 + ldsw);
  };

  int offA[2][8], offB[2][NJ];
#pragma unroll
  for (int ks = 0; ks < 2; ++ks) {
#pragma unroll
    for (int i = 0; i < 8; ++i) {
      int ra = wm * 128 + i * 16 + c16;
      offA[ks][i] = ra * 128 + (((ks * 4 + g16) ^ (ra & 7)) << 4);
    }
#pragma unroll
    for (int j = 0; j < NJ; ++j) {
      int rb = wn * (16 * NJ) + j * 16 + c16;
      offB[ks][j] = 32768 + rb * 128 + (((ks * 4 + g16) ^ (rb & 7)) << 4);
    }
  }

  const f32x4 fz = {0.f, 0.f, 0.f, 0.f};
  f32x4 acc[8][NJ];
#pragma unroll
  for (int i = 0; i < 8; ++i)
#pragma unroll
    for (int j = 0; j < NJ; ++j) acc[i][j] = fz;

  const int nkt = K >> 6;
#pragma unroll
  for (int r = 0; r < 4 + NJ; ++r) stage(0, 0, r);
  asm volatile("s_waitcnt vmcnt(0)" ::: "memory");
  __builtin_amdgcn_s_barrier();

  for (int t = 0; t < nkt; ++t) {
    const char* Ab = smem + (t & 1) * BUFSZ;
    const bool pf = (t + 1 < nkt);
    const int nb = (t + 1) & 1;
    bf16x8 bfr[2][NJ];

    {
      bf16x8 af[2][2];
#pragma unroll
      for (int ks = 0; ks < 2; ++ks) {
#pragma unroll
        for (int j = 0; j < NJ; ++j) bfr[ks][j] = *(const bf16x8*)(Ab + offB[ks][j]);
        af[ks][0] = *(const bf16x8*)(Ab + offA[ks][0]);
        af[ks][1] = *(const bf16x8*)(Ab + offA[ks][1]);
      }
      if (pf) { stage(nb, t + 1, 0); stage(nb, t + 1, 1); stage(nb, t + 1, 2); stage(nb, t + 1, 3); }
      __builtin_amdgcn_s_barrier();
      asm volatile("s_waitcnt lgkmcnt(0)" ::: "memory");
      __builtin_amdgcn_sched_barrier(0);
      __builtin_amdgcn_s_setprio(1);
#pragma unroll
      for (int ks = 0; ks < 2; ++ks)
#pragma unroll
        for (int m = 0; m < 2; ++m)
#pragma unroll
          for (int j = 0; j < NJ; ++j)
            acc[m][j] = mfma16(af[ks][m], bfr[ks][j], acc[m][j]);
      __builtin_amdgcn_s_setprio(0);
      __builtin_amdgcn_sched_barrier(0);
      __builtin_amdgcn_s_barrier();
    }

#pragma unroll
    for (int q = 1; q < 4; ++q) {
      bf16x8 af[2][2];
#pragma unroll
      for (int ks = 0; ks < 2; ++ks) {
        af[ks][0] = *(const bf16x8*)(Ab + offA[ks][q * 2]);
        af[ks][1] = *(const bf16x8*)(Ab + offA[ks][q * 2 + 1]);
      }
      if (q == 1 && pf) {
#pragma unroll
        for (int r = 0; r < NJ; ++r) stage(nb, t + 1, 4 + r);
      }
      __builtin_amdgcn_s_barrier();
      asm volatile("s_waitcnt lgkmcnt(0)" ::: "memory");
      __builtin_amdgcn_sched_barrier(0);
      __builtin_amdgcn_s_setprio(1);
#pragma unroll
      for (int ks = 0; ks < 2; ++ks)
#pragma unroll
        for (int m = 0; m < 2; ++m)
#pragma unroll
          for (int j = 0; j < NJ; ++j)
            acc[q * 2 + m][j] = mfma16(af[ks][m], bfr[ks][j], acc[q * 2 + m][j]);
      __builtin_amdgcn_s_setprio(0);
      __builtin_amdgcn_sched_barrier(0);
      if (q == 3 && pf) asm volatile("s_waitcnt vmcnt(0)" ::: "memory");
      __builtin_amdgcn_s_barrier();
    }
  }

#pragma unroll
  for (int i = 0; i < 8; ++i) {
    int gr0 = row0 + wm * 128 + i * 16 + g16 * 4;
#pragma unroll
    for (int j = 0; j < NJ; ++j) {
      int gc = col0 + wn * (16 * NJ) + j * 16 + c16;
      if constexpr (MODE == 2) {
        if (gc < 2048) {
#pragma unroll
          for (int r = 0; r < 4; ++r)
            ((bf16*)C0)[(size_t)(gr0 + r) * 2048 + gc] = (bf16)acc[i][j][r];
        } else if (gc < 2560) {
#pragma unroll
          for (int r = 0; r < 4; ++r)
            ((bf16*)C1)[(size_t)(gr0 + r) * 512 + (gc - 2048)] = (bf16)acc[i][j][r];
        } else {
          int dv = gc - 2560;
          int hkv = dv >> 7, d = dv & 127;
          size_t va = (((size_t)(gr0 >> 11) * NKV_ + hkv) * HD_ + d) * S_ + (gr0 & 2047);
          bf16x4 pk;
#pragma unroll
          for (int r = 0; r < 4; ++r) pk[r] = (bf16)acc[i][j][r];
          *(bf16x4*)((bf16*)C2 + va) = pk;
        }
      } else {
#pragma unroll
        for (int r = 0; r < 4; ++r) {
          if constexpr (MODE == 1)
            ((float*)C0)[(size_t)(gr0 + r) * N + gc] = acc[i][j][r];
          else
            ((bf16*)C0)[(size_t)(gr0 + r) * N + gc] = (bf16)acc[i][j][r];
        }
      }
    }
  }
}

// ---------------- flash attention (causal, GQA) — occupancy restructure ----------------
// QBLK=64 (4 waves x 16 q-rows), KVBLK=64. K double-buffered in LDS (32KB);
// V^T read DIRECTLY from global (L2-hot via XCD-local hkv mapping) — no V staging.
// grid = 1024 blocks -> 4 blocks/CU resident, 16 waves/CU (was 2 blocks / 8 waves).
// bid&7 -> (b,hkv) XCD-local; slot>>2 alternates heavy/light q64 tiles.

__global__ __launch_bounds__(256, 4) void attn_fwd_k(const bf16* __restrict__ Qg,
                                                     const bf16* __restrict__ Kg,
                                                     const bf16* __restrict__ VTg,
                                                     bf16* __restrict__ Og) {
  __shared__ __align__(16) bf16 Ks[2][64 * 128];   // 32 KB

  const int tid = threadIdx.x;
  const int lane = tid & 63;
  const int w = tid >> 6;
  const int g16 = lane >> 4;
  const int c16 = lane & 15;

  const int bid = blockIdx.x;
  const int xcd = bid & 7;
  const int slot = bid >> 3;            // 0..127
  const int hh = slot & 3;
  const int idx = slot >> 2;            // 0..31
  const int q64 = (idx & 1) ? (idx >> 1) : (31 - (idx >> 1));  // heavy/light interleave
  const int b = xcd >> 2;
  const int hkv = xcd & 3;
  const int h = hkv * 4 + hh;
  const int q0 = q64 * 64;
  const int qw = q0 + w * 16;           // wave's 16 q-rows

  // hoisted K fragment LDS offsets
  int kfo[4][4];
#pragma unroll
  for (int ksq = 0; ksq < 4; ++ksq)
#pragma unroll
    for (int mt = 0; mt < 4; ++mt) {
      int gp = c16 >> 2, rp = c16 & 3;
      int blk = 8 * (mt >> 1) + 2 * gp + ((mt & 1) ^ (gp & 1));
      int row = blk * 4 + rp;
      kfo[ksq][mt] = row * 256 + (((ksq * 4 + g16) ^ (row & 7)) << 4);
    }
  // hoisted K staging offsets (elements)
  int koff[4];
#pragma unroll
  for (int rd = 0; rd < 4; ++rd) {
    int rowk = (rd * 256 + w * 64 + lane) >> 4;
    koff[rd] = rowk * (NKV_ * HD_) + (((lane & 15) ^ (rowk & 7)) * 8);
  }
  // hoisted V^T global offsets (elements; +kv0 + ks*32 at use)
  int voffd[8];
#pragma unroll
  for (int dt = 0; dt < 8; ++dt)
    voffd[dt] = (dt * 16 + c16) * S_ + g16 * 8;

  bf16x8 qf[4];
#pragma unroll
  for (int ksq = 0; ksq < 4; ++ksq)
    qf[ksq] = *(const bf16x8*)(Qg + ((size_t)(b * S_ + qw + c16) * NH_ + h) * HD_ + (ksq * 4 + g16) * 8);

  float m_run = -1e30f;
  float l_run = 0.f;
  const f32x4 fz = {0.f, 0.f, 0.f, 0.f};
  f32x4 acc[8];
#pragma unroll
  for (int dt = 0; dt < 8; ++dt) acc[dt] = fz;

  const bf16* __restrict__ Kgb = Kg + ((size_t)b * S_ * NKV_ + hkv) * HD_;
  const bf16* __restrict__ Vgb = VTg + ((size_t)(b * NKV_ + hkv)) * HD_ * S_;

  auto stage = [&](int buf, int kv0) {
    const bf16* kp = Kgb + (size_t)kv0 * (NKV_ * HD_);
#pragma unroll
    for (int rd = 0; rd < 4; ++rd)
      async_copy16(kp + koff[rd], (char*)&Ks[buf][0] + (rd * 256 + w * 64) * 16);
  };

  const int ntiles = q64 + 1;
  stage(0, 0);
  int cur = 0;

  for (int t = 0; t < ntiles; ++t) {
    __syncthreads();
    if (t + 1 < ntiles) stage(cur ^ 1, (t + 1) * 64);
    const int kv0 = t * 64;

    if (kv0 <= qw + 15) {
      const char* KsC = (const char*)&Ks[cur][0];

      f32x4 sc[4];
#pragma unroll
      for (int mt = 0; mt < 4; ++mt) sc[mt] = fz;

      __builtin_amdgcn_s_setprio(1);
#pragma unroll
      for (int ksq = 0; ksq < 4; ++ksq) {
        bf16x8 kf[4];
#pragma unroll
        for (int mt = 0; mt < 4; ++mt)
          kf[mt] = *(const bf16x8*)(KsC + kfo[ksq][mt]);
#pragma unroll
        for (int mt = 0; mt < 4; ++mt)
          sc[mt] = mfma16(kf[mt], qf[ksq], sc[mt]);
      }
      __builtin_amdgcn_s_setprio(0);

      if (kv0 + 63 > qw) {
        int qa = qw + c16;
#pragma unroll
        for (int mt = 0; mt < 4; ++mt) {
          int blk = 8 * (mt >> 1) + 2 * g16 + ((mt & 1) ^ (g16 & 1));
#pragma unroll
          for (int r = 0; r < 4; ++r) {
            int ka = kv0 + blk * 4 + r;
            if (ka > qa) sc[mt][r] = -1e30f;
          }
        }
      }

      float mx = sc[0][0];
#pragma unroll
      for (int mt = 0; mt < 4; ++mt)
#pragma unroll
        for (int r = 0; r < 4; ++r) mx = fmaxf(mx, sc[mt][r]);
      mx = fmaxf(mx, __shfl_xor(mx, 16));
      mx = fmaxf(mx, __shfl_xor(mx, 32));
      if (__any(mx > m_run + 8.f)) {
        float mn = fmaxf(m_run, mx);
        float corr = exp2f(m_run - mn);
        m_run = mn;
        l_run *= corr;
#pragma unroll
        for (int dt = 0; dt < 8; ++dt) acc[dt] *= corr;
      }
      float sum = 0.f;
#pragma unroll
      for (int mt = 0; mt < 4; ++mt)
#pragma unroll
        for (int r = 0; r < 4; ++r) {
          float p = exp2f(sc[mt][r] - m_run);
          sc[mt][r] = p;
          sum += p;
        }
      sum += __shfl_xor(sum, 16);
      sum += __shfl_xor(sum, 32);
      l_run += sum;

      bf16x8 pa[2];
#pragma unroll
      for (int ks = 0; ks < 2; ++ks) {
        f32x4 sA = (g16 & 1) ? sc[2 * ks + 1] : sc[2 * ks];
        f32x4 sB = (g16 & 1) ? sc[2 * ks] : sc[2 * ks + 1];
        bf16x8 tf;
        tf[0] = (bf16)sA[0]; tf[1] = (bf16)sA[1]; tf[2] = (bf16)sA[2]; tf[3] = (bf16)sA[3];
        tf[4] = (bf16)sB[0]; tf[5] = (bf16)sB[1]; tf[6] = (bf16)sB[2]; tf[7] = (bf16)sB[3];
        pa[ks] = tf;
      }

      // PV: V^T fragments straight from global (L2-hot)
      __builtin_amdgcn_s_setprio(1);
#pragma unroll
      for (int ks = 0; ks < 2; ++ks)
#pragma unroll
        for (int dt = 0; dt < 8; ++dt) {
          bf16x8 vf = *(const bf16x8*)(Vgb + voffd[dt] + kv0 + ks * 32);
          acc[dt] = mfma16(vf, pa[ks], acc[dt]);
        }
      __builtin_amdgcn_s_setprio(0);
    }
    cur ^= 1;
  }

  float inv = 1.0f / l_run;
  size_t base = ((size_t)(b * S_ + qw + c16) * NH_ + h) * HD_ + g16 * 4;
#pragma unroll
  for (int dt = 0; dt < 8; ++dt) {
    bf16x4 ov;
#pragma unroll
    for (int r = 0; r < 4; ++r) ov[r] = (bf16)(acc[dt][r] * inv);
    *(bf16x4*)(Og + base + dt * 16) = ov;
  }
}

// ---------------- launcher ----------------

extern "C" void kernel_launch(void* const* d_in, const int* in_sizes, int n_in,
                              void* d_out, int out_size, void* d_ws, size_t ws_size,
                              hipStream_t stream) {
  const float* x  = (const float*)d_in[0];
  const int* pos  = (const int*)d_in[2];
  const float* Wq = (const float*)d_in[3];
  const float* Wk = (const float*)d_in[4];
  const float* Wv = (const float*)d_in[5];
  const float* Wo = (const float*)d_in[6];

  char* ws = (char*)d_ws;
  size_t off = 0;
  auto alloc = [&](size_t bytes) -> char* {
    char* p = ws + off;
    off += (bytes + 255) & ~(size_t)255;
    return p;
  };
  const size_t rows = (size_t)B_ * S_;
  bf16* xb    = (bf16*)alloc(rows * H_ * 2);
  bf16* bq    = (bf16*)alloc(rows * (NH_ * HD_) * 2);
  bf16* batt  = (bf16*)alloc(rows * (NH_ * HD_) * 2);
  bf16* WqkvT = (bf16*)alloc((size_t)3072 * H_ * 2);
  bf16* WoT   = (bf16*)alloc((size_t)H_ * H_ * 2);
  bf16* bk    = (bf16*)alloc(rows * (NKV_ * HD_) * 2);
  bf16* VT    = (bf16*)alloc(rows * (NKV_ * HD_) * 2); // [b][hkv][d][S]
  float2* tab = (float2*)alloc((size_t)S_ * 64 * sizeof(float2));

  auto* fqkv = gemm256_k<2, 3>;
  auto* fo   = gemm256_k<1, 2>;
  const int ldsQKV = 2 * (32768 + 3 * 8192);  // 114688
  const int ldsO   = 2 * (32768 + 2 * 8192);  // 98304
  (void)hipFuncSetAttribute((const void*)fqkv, hipFuncAttributeMaxDynamicSharedMemorySize, ldsQKV);
  (void)hipFuncSetAttribute((const void*)fo, hipFuncAttributeMaxDynamicSharedMemorySize, ldsO);

  // merged prep: transposes + x convert + rope table in one launch
  prep_all_k<<<18944, 256, 0, stream>>>(x, Wq, Wk, Wv, Wo, xb, WqkvT, WoT, tab);

  // fused QKV projection: 256x192 tiles, grid 16x16 = 256 blocks exact
  gemm256_k<2, 3><<<dim3(16, 16), 512, ldsQKV, stream>>>(xb, WqkvT, bq, bk, VT, 4096, 3072, 2048);

  // merged RoPE for Q and K (vectorized)
  rope_both_k<<<2560, 256, 0, stream>>>(bq, bk, pos, tab);

  // attention: 1024 blocks (QBLK=64), XCD-local KV, V direct-from-global
  attn_fwd_k<<<dim3(1024), 256, 0, stream>>>(bq, bk, VT, batt);

  // output projection (f32 out): 256x128 tiles, grid 16x16 = 256 blocks exact
  gemm256_k<1, 2><<<dim3(16, 16), 512, ldsO, stream>>>(batt, WoT, d_out, nullptr, nullptr, 4096, 2048, 2048);
}

// Round 13
// 193.791 us; speedup vs baseline: 1.7018x; 1.7018x over previous
//
#include <hip/hip_runtime.h>
#include <hip/hip_bf16.h>
#include <stdint.h>
#include <math.h>

#define B_ 2
#define S_ 2048
#define H_ 2048
#define NH_ 16
#define NKV_ 4
#define HD_ 128

typedef __bf16 bf16;
typedef __bf16 bf16x8 __attribute__((ext_vector_type(8)));
typedef __bf16 bf16x4 __attribute__((ext_vector_type(4)));
typedef float f32x4 __attribute__((ext_vector_type(4)));

__device__ __forceinline__ void async_copy16(const void* g, void* l) {
  __builtin_amdgcn_global_load_lds(
      (const __attribute__((address_space(1))) void*)(uintptr_t)g,
      (__attribute__((address_space(3))) void*)(uintptr_t)l,
      16, 0, 0);
}

__device__ __forceinline__ f32x4 mfma16(bf16x8 a, bf16x8 b, f32x4 c) {
  return __builtin_amdgcn_mfma_f32_16x16x32_bf16(a, b, c, 0, 0, 0);
}

// ---------------- merged prep kernel ----------------
// bids [0,10240): weight transposes (Wq|Wk|Wv -> WqkvT rows {0,2048,2560}; Wo -> WoT)
// bids [10240,18432): x f32 -> bf16 (4 els/thread)
// bids [18432,18944): RoPE cos/sin table

__global__ void prep_all_k(const float* __restrict__ x,
                           const float* __restrict__ Wq, const float* __restrict__ Wk,
                           const float* __restrict__ Wv, const float* __restrict__ Wo,
                           bf16* __restrict__ xb, bf16* __restrict__ WqkvT,
                           bf16* __restrict__ WoT, float2* __restrict__ tab) {
  __shared__ float tile[32][33];
  const int bid = blockIdx.x;
  const int tid = threadIdx.x;

  if (bid < 10240) {
    const float* W; bf16* Wt; int N, bx, by;
    if (bid < 4096)      { W = Wq; Wt = WqkvT;                       N = 2048; int b2 = bid;        bx = b2 & 63; by = b2 >> 6; }
    else if (bid < 5120) { W = Wk; Wt = WqkvT + (size_t)2048 * 2048; N = 512;  int b2 = bid - 4096; bx = b2 & 15; by = b2 >> 4; }
    else if (bid < 6144) { W = Wv; Wt = WqkvT + (size_t)2560 * 2048; N = 512;  int b2 = bid - 5120; bx = b2 & 15; by = b2 >> 4; }
    else                 { W = Wo; Wt = WoT;                         N = 2048; int b2 = bid - 6144; bx = b2 & 63; by = b2 >> 6; }
    const int K = 2048;
    int n0 = bx * 32, k0 = by * 32;
    int tx = tid & 31, ty = tid >> 5;   // (32, 8)
#pragma unroll
    for (int j = 0; j < 32; j += 8)
      tile[ty + j][tx] = W[(size_t)(k0 + ty + j) * N + n0 + tx];
    __syncthreads();
#pragma unroll
    for (int j = 0; j < 32; j += 8)
      Wt[(size_t)(n0 + ty + j) * K + k0 + tx] = (bf16)tile[tx][ty + j];
  } else if (bid < 18432) {
    int i = ((bid - 10240) * 256 + tid) * 4;
    float4 v = *(const float4*)(x + i);
    bf16x4 r;
    r[0] = (bf16)v.x; r[1] = (bf16)v.y; r[2] = (bf16)v.z; r[3] = (bf16)v.w;
    *(bf16x4*)(xb + i) = r;
  } else {
    int i = (bid - 18432) * 256 + tid;   // S_*64
    int p = i >> 6, d = i & 63;
    float invf = expf(-((float)(2 * d) / 128.0f) * 9.210340371976184f);
    float fr = (float)p * invf;
    float sv, cv;
    sincosf(fr, &sv, &cv);
    tab[i] = make_float2(cv, sv);
  }
}

// vectorized RoPE: each thread handles 8 (d, d+64) pairs via bf16x8 loads (G13).
__global__ void rope_apply_v8_k(bf16* __restrict__ t, const int* __restrict__ pos_ids,
                                const float2* __restrict__ tab, int hshift, int hmask,
                                float scale) {
  int i = blockIdx.x * 256 + threadIdx.x;   // rows*heads*8
  int g = i & 7;                             // 8-wide chunk of d in [0,64)
  int tmp = i >> 3;
  int h = tmp & hmask;
  int row = tmp >> hshift;
  int pos = pos_ids[row];
  size_t base = (((size_t)row << hshift) + h) * HD_ + g * 8;
  const float2* tb = tab + pos * 64 + g * 8;
  bf16x8 lo = *(const bf16x8*)(t + base);
  bf16x8 hi = *(const bf16x8*)(t + base + 64);
  float4 t0 = *(const float4*)(tb);
  float4 t1 = *(const float4*)(tb + 2);
  float4 t2 = *(const float4*)(tb + 4);
  float4 t3 = *(const float4*)(tb + 6);
  float cs[8], sn[8];
  cs[0]=t0.x; sn[0]=t0.y; cs[1]=t0.z; sn[1]=t0.w;
  cs[2]=t1.x; sn[2]=t1.y; cs[3]=t1.z; sn[3]=t1.w;
  cs[4]=t2.x; sn[4]=t2.y; cs[5]=t2.z; sn[5]=t2.w;
  cs[6]=t3.x; sn[6]=t3.y; cs[7]=t3.z; sn[7]=t3.w;
  bf16x8 olo, ohi;
#pragma unroll
  for (int j = 0; j < 8; ++j) {
    float a = (float)lo[j], b = (float)hi[j];
    olo[j] = (bf16)((a * cs[j] - b * sn[j]) * scale);
    ohi[j] = (bf16)((b * cs[j] + a * sn[j]) * scale);
  }
  *(bf16x8*)(t + base) = olo;
  *(bf16x8*)(t + base + 64) = ohi;
}

// ---------------- 256xBN 8-wave GEMM (m201-style) ----------------

template <int MODE, int NJ>
__global__ __launch_bounds__(512) void gemm256_k(const bf16* __restrict__ A,
                                                 const bf16* __restrict__ Bt,
                                                 void* __restrict__ C0,
                                                 void* __restrict__ C1,
                                                 void* __restrict__ C2,
                                                 int M, int N, int K) {
  extern __shared__ __align__(16) char smem[];
  constexpr int BUFSZ = 32768 + NJ * 8192;
  const int tid = threadIdx.x;
  const int lane = tid & 63;
  const int w = tid >> 6;
  const int wm = w >> 2;          // 0..1 (M half)
  const int wn = w & 3;           // 0..3 (N quarter)
  const int g16 = lane >> 4, c16 = lane & 15;
  const int row0 = blockIdx.y * 256;
  const int col0 = blockIdx.x * (NJ * 64);
  const int srow = tid >> 3;
  const int sslot = tid & 7;
  const int ldsw = w * 1024;

  auto stage = [&](int buf, int kt, int r) {
    int rr = (r < 4) ? r : r - 4;
    int row = rr * 64 + srow;
    int ss = sslot ^ (row & 7);
    const bf16* src = (r < 4) ? (A + (size_t)(row0 + row) * K)
                              : (Bt + (size_t)(col0 + row) * K);
    async_copy16(src + (kt << 6) + ss * 8,
                 smem + buf * BUFSZ + ((r < 4) ? 0 : 32768) + rr * 8192 + ldsw);
  };

  int offA[2][8], offB[2][NJ];
#pragma unroll
  for (int ks = 0; ks < 2; ++ks) {
#pragma unroll
    for (int i = 0; i < 8; ++i) {
      int ra = wm * 128 + i * 16 + c16;
      offA[ks][i] = ra * 128 + (((ks * 4 + g16) ^ (ra & 7)) << 4);
    }
#pragma unroll
    for (int j = 0; j < NJ; ++j) {
      int rb = wn * (16 * NJ) + j * 16 + c16;
      offB[ks][j] = 32768 + rb * 128 + (((ks * 4 + g16) ^ (rb & 7)) << 4);
    }
  }

  const f32x4 fz = {0.f, 0.f, 0.f, 0.f};
  f32x4 acc[8][NJ];
#pragma unroll
  for (int i = 0; i < 8; ++i)
#pragma unroll
    for (int j = 0; j < NJ; ++j) acc[i][j] = fz;

  const int nkt = K >> 6;
#pragma unroll
  for (int r = 0; r < 4 + NJ; ++r) stage(0, 0, r);
  asm volatile("s_waitcnt vmcnt(0)" ::: "memory");
  __builtin_amdgcn_s_barrier();

  for (int t = 0; t < nkt; ++t) {
    const char* Ab = smem + (t & 1) * BUFSZ;
    const bool pf = (t + 1 < nkt);
    const int nb = (t + 1) & 1;
    bf16x8 bfr[2][NJ];

    {
      bf16x8 af[2][2];
#pragma unroll
      for (int ks = 0; ks < 2; ++ks) {
#pragma unroll
        for (int j = 0; j < NJ; ++j) bfr[ks][j] = *(const bf16x8*)(Ab + offB[ks][j]);
        af[ks][0] = *(const bf16x8*)(Ab + offA[ks][0]);
        af[ks][1] = *(const bf16x8*)(Ab + offA[ks][1]);
      }
      if (pf) { stage(nb, t + 1, 0); stage(nb, t + 1, 1); stage(nb, t + 1, 2); stage(nb, t + 1, 3); }
      __builtin_amdgcn_s_barrier();
      asm volatile("s_waitcnt lgkmcnt(0)" ::: "memory");
      __builtin_amdgcn_sched_barrier(0);
      __builtin_amdgcn_s_setprio(1);
#pragma unroll
      for (int ks = 0; ks < 2; ++ks)
#pragma unroll
        for (int m = 0; m < 2; ++m)
#pragma unroll
          for (int j = 0; j < NJ; ++j)
            acc[m][j] = mfma16(af[ks][m], bfr[ks][j], acc[m][j]);
      __builtin_amdgcn_s_setprio(0);
      __builtin_amdgcn_sched_barrier(0);
      __builtin_amdgcn_s_barrier();
    }

#pragma unroll
    for (int q = 1; q < 4; ++q) {
      bf16x8 af[2][2];
#pragma unroll
      for (int ks = 0; ks < 2; ++ks) {
        af[ks][0] = *(const bf16x8*)(Ab + offA[ks][q * 2]);
        af[ks][1] = *(const bf16x8*)(Ab + offA[ks][q * 2 + 1]);
      }
      if (q == 1 && pf) {
#pragma unroll
        for (int r = 0; r < NJ; ++r) stage(nb, t + 1, 4 + r);
      }
      __builtin_amdgcn_s_barrier();
      asm volatile("s_waitcnt lgkmcnt(0)" ::: "memory");
      __builtin_amdgcn_sched_barrier(0);
      __builtin_amdgcn_s_setprio(1);
#pragma unroll
      for (int ks = 0; ks < 2; ++ks)
#pragma unroll
        for (int m = 0; m < 2; ++m)
#pragma unroll
          for (int j = 0; j < NJ; ++j)
            acc[q * 2 + m][j] = mfma16(af[ks][m], bfr[ks][j], acc[q * 2 + m][j]);
      __builtin_amdgcn_s_setprio(0);
      __builtin_amdgcn_sched_barrier(0);
      if (q == 3 && pf) asm volatile("s_waitcnt vmcnt(0)" ::: "memory");
      __builtin_amdgcn_s_barrier();
    }
  }

#pragma unroll
  for (int i = 0; i < 8; ++i) {
    int gr0 = row0 + wm * 128 + i * 16 + g16 * 4;
#pragma unroll
    for (int j = 0; j < NJ; ++j) {
      int gc = col0 + wn * (16 * NJ) + j * 16 + c16;
      if constexpr (MODE == 2) {
        if (gc < 2048) {
#pragma unroll
          for (int r = 0; r < 4; ++r)
            ((bf16*)C0)[(size_t)(gr0 + r) * 2048 + gc] = (bf16)acc[i][j][r];
        } else if (gc < 2560) {
#pragma unroll
          for (int r = 0; r < 4; ++r)
            ((bf16*)C1)[(size_t)(gr0 + r) * 512 + (gc - 2048)] = (bf16)acc[i][j][r];
        } else {
          int dv = gc - 2560;
          int hkv = dv >> 7, d = dv & 127;
          size_t va = (((size_t)(gr0 >> 11) * NKV_ + hkv) * HD_ + d) * S_ + (gr0 & 2047);
          bf16x4 pk;
#pragma unroll
          for (int r = 0; r < 4; ++r) pk[r] = (bf16)acc[i][j][r];
          *(bf16x4*)((bf16*)C2 + va) = pk;
        }
      } else {
#pragma unroll
        for (int r = 0; r < 4; ++r) {
          if constexpr (MODE == 1)
            ((float*)C0)[(size_t)(gr0 + r) * N + gc] = acc[i][j][r];
          else
            ((bf16*)C0)[(size_t)(gr0 + r) * N + gc] = (bf16)acc[i][j][r];
        }
      }
    }
  }
}

// ---------------- 128x256 8-wave pipelined GEMM (O-proj: 256 blocks exact) ----------------

template <int MODE>
__global__ __launch_bounds__(512) void gemm8_k(const bf16* __restrict__ A,
                                               const bf16* __restrict__ Bt,
                                               void* __restrict__ C0,
                                               void* __restrict__ C1,
                                               void* __restrict__ C2,
                                               int M, int N, int K) {
  extern __shared__ __align__(16) char smem[];
  const int tid = threadIdx.x;
  const int lane = tid & 63;
  const int w = tid >> 6;
  const int wm = w >> 2;
  const int wn = w & 3;
  const int g16 = lane >> 4, c16 = lane & 15;
  const int row0 = blockIdx.y * 128;
  const int col0 = blockIdx.x * 256;
  const int srow = tid >> 3;
  const int sslot = tid & 7;
  const int ldsw = w * 1024;

  auto stageA = [&](int s, int kt, int r) {
    int row = r * 64 + srow;
    int ss = sslot ^ (row & 7);
    async_copy16(A + (size_t)(row0 + row) * K + (kt << 6) + ss * 8,
                 smem + s * 49152 + r * 8192 + ldsw);
  };
  auto stageB = [&](int s, int kt, int r) {
    int row = r * 64 + srow;
    int ss = sslot ^ (row & 7);
    async_copy16(Bt + (size_t)(col0 + row) * K + (kt << 6) + ss * 8,
                 smem + s * 49152 + 16384 + r * 8192 + ldsw);
  };

  int offA[2][4], offB[2][4];
#pragma unroll
  for (int ks = 0; ks < 2; ++ks) {
#pragma unroll
    for (int i = 0; i < 4; ++i) {
      int ra = wm * 64 + i * 16 + c16;
      offA[ks][i] = ra * 128 + (((ks * 4 + g16) ^ (ra & 7)) << 4);
      int rb = wn * 64 + i * 16 + c16;
      offB[ks][i] = rb * 128 + (((ks * 4 + g16) ^ (rb & 7)) << 4);
    }
  }

  const f32x4 fz = {0.f, 0.f, 0.f, 0.f};
  f32x4 acc[4][4];
#pragma unroll
  for (int i = 0; i < 4; ++i)
#pragma unroll
    for (int j = 0; j < 4; ++j) acc[i][j] = fz;

  const int nkt = K >> 6;
#pragma unroll
  for (int r = 0; r < 2; ++r) stageA(0, 0, r);
#pragma unroll
  for (int r = 0; r < 4; ++r) stageB(0, 0, r);
#pragma unroll
  for (int r = 0; r < 2; ++r) stageA(1, 1, r);
#pragma unroll
  for (int r = 0; r < 4; ++r) stageB(1, 1, r);
  asm volatile("s_waitcnt vmcnt(6)" ::: "memory");
  __builtin_amdgcn_s_barrier();

  int ct = 0, pt = 2;
  for (int t = 0; t < nkt; ++t) {
    const char* Ab = smem + ct * 49152;
    const char* Bb = Ab + 16384;
    const bool pf = (t + 2 < nkt);
    const int kpf = t + 2;
    bf16x8 af[4], bfr[4];

#pragma unroll
    for (int i = 0; i < 4; ++i) af[i] = *(const bf16x8*)(Ab + offA[0][i]);
#pragma unroll
    for (int j = 0; j < 4; ++j) bfr[j] = *(const bf16x8*)(Bb + offB[0][j]);
    if (pf) { stageA(pt, kpf, 0); stageA(pt, kpf, 1); stageB(pt, kpf, 0); }
    __builtin_amdgcn_s_barrier();
    asm volatile("s_waitcnt lgkmcnt(0)" ::: "memory");
    __builtin_amdgcn_sched_barrier(0);
    __builtin_amdgcn_s_setprio(1);
#pragma unroll
    for (int i = 0; i < 4; ++i)
#pragma unroll
      for (int j = 0; j < 4; ++j) acc[i][j] = mfma16(af[i], bfr[j], acc[i][j]);
    __builtin_amdgcn_s_setprio(0);
    __builtin_amdgcn_sched_barrier(0);
    __builtin_amdgcn_s_barrier();

#pragma unroll
    for (int i = 0; i < 4; ++i) af[i] = *(const bf16x8*)(Ab + offA[1][i]);
#pragma unroll
    for (int j = 0; j < 4; ++j) bfr[j] = *(const bf16x8*)(Bb + offB[1][j]);
    if (pf) { stageB(pt, kpf, 1); stageB(pt, kpf, 2); stageB(pt, kpf, 3); }
    if (pf) asm volatile("s_waitcnt vmcnt(6)" ::: "memory");
    else    asm volatile("s_waitcnt vmcnt(0)" ::: "memory");
    __builtin_amdgcn_s_barrier();
    asm volatile("s_waitcnt lgkmcnt(0)" ::: "memory");
    __builtin_amdgcn_sched_barrier(0);
    __builtin_amdgcn_s_setprio(1);
#pragma unroll
    for (int i = 0; i < 4; ++i)
#pragma unroll
      for (int j = 0; j < 4; ++j) acc[i][j] = mfma16(af[i], bfr[j], acc[i][j]);
    __builtin_amdgcn_s_setprio(0);
    __builtin_amdgcn_sched_barrier(0);
    __builtin_amdgcn_s_barrier();

    ct = (ct == 2) ? 0 : ct + 1;
    pt = (pt == 2) ? 0 : pt + 1;
  }

#pragma unroll
  for (int i = 0; i < 4; ++i) {
    int gr0 = row0 + wm * 64 + i * 16 + g16 * 4;
#pragma unroll
    for (int j = 0; j < 4; ++j) {
      int gc = col0 + wn * 64 + j * 16 + c16;
#pragma unroll
      for (int r = 0; r < 4; ++r) {
        if constexpr (MODE == 1)
          ((float*)C0)[(size_t)(gr0 + r) * N + gc] = acc[i][j][r];
        else
          ((bf16*)C0)[(size_t)(gr0 + r) * N + gc] = (bf16)acc[i][j][r];
      }
    }
  }
}

// ---------------- flash attention (causal, GQA) — r6 structure + robust pairing ----------------
// QBLK=128 (4 waves x 32 q-rows), KVBLK=64, swapped QK^T with permuted K rows so P
// is fully in-lane for PV. exp2-domain softmax + defer-max + setprio.
// par = (bid&1)^(bid>>8): bids differing by 1 OR 256 get opposite heavy/light parity.

__global__ __launch_bounds__(256, 2) void attn_fwd_k(const bf16* __restrict__ Qg,
                                                     const bf16* __restrict__ Kg,
                                                     const bf16* __restrict__ VTg,
                                                     bf16* __restrict__ Og) {
  __shared__ __align__(16) bf16 Ks[2][64 * 128];
  __shared__ __align__(16) bf16 Vt[2][128 * 64];

  const int tid = threadIdx.x;
  const int lane = tid & 63;
  const int w = tid >> 6;
  const int g16 = lane >> 4;
  const int c16 = lane & 15;

  const int bid = blockIdx.x;
  const int i_ = ((bid >> 8) << 7) | ((bid & 255) >> 1);
  const int par = ((bid & 1) ^ (bid >> 8)) & 1;
  const int qb = par ? (i_ >> 5) : (15 - (i_ >> 5));
  const int bh = i_ & 31;
  const int b = bh >> 4;
  const int h = bh & 15;
  const int hkv = h >> 2;
  const int q0 = qb * 128;
  const int qw = q0 + w * 32;

  bf16x8 qf[2][4];
#pragma unroll
  for (int nq = 0; nq < 2; ++nq)
#pragma unroll
    for (int ksq = 0; ksq < 4; ++ksq)
      qf[nq][ksq] = *(const bf16x8*)(Qg + ((size_t)(b * S_ + qw + nq * 16 + c16) * NH_ + h) * HD_ + (ksq * 4 + g16) * 8);

  float m_run[2] = {-1e30f, -1e30f};
  float l_run[2] = {0.f, 0.f};
  const f32x4 fz = {0.f, 0.f, 0.f, 0.f};
  f32x4 acc[2][8];
#pragma unroll
  for (int nq = 0; nq < 2; ++nq)
#pragma unroll
    for (int dt = 0; dt < 8; ++dt) acc[nq][dt] = fz;

  const size_t kbase = ((size_t)b * S_ * NKV_ + hkv) * HD_;
  const size_t vbase = ((size_t)(b * NKV_ + hkv)) * HD_ * S_;

  auto stage = [&](int buf, int kv0) {
#pragma unroll
    for (int rd = 0; rd < 4; ++rd) {
      int Lb = rd * 256 + w * 64;
      int row = (Lb + lane) >> 4;
      int ssl = (lane & 15) ^ (row & 7);
      async_copy16(Kg + kbase + (size_t)(kv0 + row) * (NKV_ * HD_) + ssl * 8,
                   (char*)&Ks[buf][0] + Lb * 16);
    }
#pragma unroll
    for (int rd = 0; rd < 4; ++rd) {
      int Lb = rd * 256 + w * 64;
      int row = (Lb + lane) >> 3;
      int ssl = (lane & 7) ^ (row & 7);
      async_copy16(VTg + vbase + (size_t)row * S_ + kv0 + ssl * 8,
                   (char*)&Vt[buf][0] + Lb * 16);
    }
  };

  const int ntiles = 2 * qb + 2;
  stage(0, 0);
  int cur = 0;

  for (int t = 0; t < ntiles; ++t) {
    __syncthreads();
    if (t + 1 < ntiles) stage(cur ^ 1, (t + 1) * 64);
    const int kv0 = t * 64;

    if (kv0 <= qw + 31) {
      const bf16* KsC = &Ks[cur][0];
      const bf16* VtC = &Vt[cur][0];

      f32x4 sc[2][4];
#pragma unroll
      for (int nq = 0; nq < 2; ++nq)
#pragma unroll
        for (int mt = 0; mt < 4; ++mt) sc[nq][mt] = fz;

      __builtin_amdgcn_s_setprio(1);
#pragma unroll
      for (int ksq = 0; ksq < 4; ++ksq) {
        bf16x8 kf[4];
#pragma unroll
        for (int mt = 0; mt < 4; ++mt) {
          int gp = c16 >> 2, rp = c16 & 3;
          int blk = 8 * (mt >> 1) + 2 * gp + ((mt & 1) ^ (gp & 1));
          int row = blk * 4 + rp;
          kf[mt] = *(const bf16x8*)((const char*)KsC + row * 256 + (((ksq * 4 + g16) ^ (row & 7)) << 4));
        }
#pragma unroll
        for (int nq = 0; nq < 2; ++nq)
#pragma unroll
          for (int mt = 0; mt < 4; ++mt)
            sc[nq][mt] = mfma16(kf[mt], qf[nq][ksq], sc[nq][mt]);
      }
      __builtin_amdgcn_s_setprio(0);

      if (kv0 + 63 > qw) {
#pragma unroll
        for (int nq = 0; nq < 2; ++nq) {
          int qa = qw + nq * 16 + c16;
#pragma unroll
          for (int mt = 0; mt < 4; ++mt) {
            int blk = 8 * (mt >> 1) + 2 * g16 + ((mt & 1) ^ (g16 & 1));
#pragma unroll
            for (int r = 0; r < 4; ++r) {
              int ka = kv0 + blk * 4 + r;
              if (ka > qa) sc[nq][mt][r] = -1e30f;
            }
          }
        }
      }

      float mx[2];
#pragma unroll
      for (int nq = 0; nq < 2; ++nq) {
        float v = sc[nq][0][0];
#pragma unroll
        for (int mt = 0; mt < 4; ++mt)
#pragma unroll
          for (int r = 0; r < 4; ++r) v = fmaxf(v, sc[nq][mt][r]);
        v = fmaxf(v, __shfl_xor(v, 16));
        v = fmaxf(v, __shfl_xor(v, 32));
        mx[nq] = v;
      }
      if (__any((mx[0] > m_run[0] + 8.f) || (mx[1] > m_run[1] + 8.f))) {
#pragma unroll
        for (int nq = 0; nq < 2; ++nq) {
          float mn = fmaxf(m_run[nq], mx[nq]);
          float corr = exp2f(m_run[nq] - mn);
          m_run[nq] = mn;
          l_run[nq] *= corr;
#pragma unroll
          for (int dt = 0; dt < 8; ++dt) acc[nq][dt] *= corr;
        }
      }
#pragma unroll
      for (int nq = 0; nq < 2; ++nq) {
        float sum = 0.f;
#pragma unroll
        for (int mt = 0; mt < 4; ++mt)
#pragma unroll
          for (int r = 0; r < 4; ++r) {
            float p = exp2f(sc[nq][mt][r] - m_run[nq]);
            sc[nq][mt][r] = p;
            sum += p;
          }
        sum += __shfl_xor(sum, 16);
        sum += __shfl_xor(sum, 32);
        l_run[nq] += sum;
      }

      bf16x8 pa[2][2];
#pragma unroll
      for (int nq = 0; nq < 2; ++nq)
#pragma unroll
        for (int ks = 0; ks < 2; ++ks) {
          f32x4 sA = (g16 & 1) ? sc[nq][2 * ks + 1] : sc[nq][2 * ks];
          f32x4 sB = (g16 & 1) ? sc[nq][2 * ks] : sc[nq][2 * ks + 1];
          bf16x8 tf;
          tf[0] = (bf16)sA[0]; tf[1] = (bf16)sA[1]; tf[2] = (bf16)sA[2]; tf[3] = (bf16)sA[3];
          tf[4] = (bf16)sB[0]; tf[5] = (bf16)sB[1]; tf[6] = (bf16)sB[2]; tf[7] = (bf16)sB[3];
          pa[nq][ks] = tf;
        }

      __builtin_amdgcn_s_setprio(1);
#pragma unroll
      for (int ks = 0; ks < 2; ++ks)
#pragma unroll
        for (int dt = 0; dt < 8; ++dt) {
          int rv = dt * 16 + c16;
          bf16x8 vf = *(const bf16x8*)((const char*)VtC + rv * 128 + (((ks * 4 + g16) ^ (rv & 7)) << 4));
          acc[0][dt] = mfma16(vf, pa[0][ks], acc[0][dt]);
          acc[1][dt] = mfma16(vf, pa[1][ks], acc[1][dt]);
        }
      __builtin_amdgcn_s_setprio(0);
    }
    cur ^= 1;
  }

#pragma unroll
  for (int nq = 0; nq < 2; ++nq) {
    float inv = 1.0f / l_run[nq];
    size_t base = ((size_t)(b * S_ + qw + nq * 16 + c16) * NH_ + h) * HD_ + g16 * 4;
#pragma unroll
    for (int dt = 0; dt < 8; ++dt) {
      bf16x4 ov;
#pragma unroll
      for (int r = 0; r < 4; ++r) ov[r] = (bf16)(acc[nq][dt][r] * inv);
      *(bf16x4*)(Og + base + dt * 16) = ov;
    }
  }
}

// ---------------- launcher ----------------

extern "C" void kernel_launch(void* const* d_in, const int* in_sizes, int n_in,
                              void* d_out, int out_size, void* d_ws, size_t ws_size,
                              hipStream_t stream) {
  const float* x  = (const float*)d_in[0];
  const int* pos  = (const int*)d_in[2];
  const float* Wq = (const float*)d_in[3];
  const float* Wk = (const float*)d_in[4];
  const float* Wv = (const float*)d_in[5];
  const float* Wo = (const float*)d_in[6];

  char* ws = (char*)d_ws;
  size_t off = 0;
  auto alloc = [&](size_t bytes) -> char* {
    char* p = ws + off;
    off += (bytes + 255) & ~(size_t)255;
    return p;
  };
  const size_t rows = (size_t)B_ * S_;
  bf16* xb    = (bf16*)alloc(rows * H_ * 2);
  bf16* bq    = (bf16*)alloc(rows * (NH_ * HD_) * 2);
  bf16* batt  = (bf16*)alloc(rows * (NH_ * HD_) * 2);
  bf16* WqkvT = (bf16*)alloc((size_t)3072 * H_ * 2);   // rows: Wq 0..2047 | Wk ..2559 | Wv ..3071
  bf16* WoT   = (bf16*)alloc((size_t)H_ * H_ * 2);
  bf16* bk    = (bf16*)alloc(rows * (NKV_ * HD_) * 2);
  bf16* VT    = (bf16*)alloc(rows * (NKV_ * HD_) * 2); // [b][hkv][d][S]
  float2* tab = (float2*)alloc((size_t)S_ * 64 * sizeof(float2));

  auto* fqkv = gemm256_k<2, 3>;
  auto* fo   = gemm8_k<1>;
  const int lds256 = 2 * (32768 + 3 * 8192);  // 114688
  const int lds8   = 3 * 49152;               // 147456
  (void)hipFuncSetAttribute((const void*)fqkv, hipFuncAttributeMaxDynamicSharedMemorySize, lds256);
  (void)hipFuncSetAttribute((const void*)fo, hipFuncAttributeMaxDynamicSharedMemorySize, lds8);

  // merged prep: transposes + x convert + rope table in one launch
  prep_all_k<<<18944, 256, 0, stream>>>(x, Wq, Wk, Wv, Wo, xb, WqkvT, WoT, tab);

  // fused QKV projection: 256x192 tiles, grid 16x16 = 256 blocks exact
  gemm256_k<2, 3><<<dim3(16, 16), 512, lds256, stream>>>(xb, WqkvT, bq, bk, VT, 4096, 3072, 2048);

  // RoPE (vectorized): Q gets 1/sqrt(HD) * log2(e) folded in (exp2-domain softmax)
  rope_apply_v8_k<<<(4096 * NH_ * 8) / 256, 256, 0, stream>>>(bq, pos, tab, 4, 15, 0.12753102f);
  rope_apply_v8_k<<<(4096 * NKV_ * 8) / 256, 256, 0, stream>>>(bk, pos, tab, 2, 3, 1.0f);

  // attention: 512 blocks, parity-paired heavy/light
  attn_fwd_k<<<dim3(512), 256, 0, stream>>>(bq, bk, VT, batt);

  // output projection (f32 out): 128x256 tile, 8x32 = 256 blocks exact fit
  gemm8_k<1><<<dim3(8, 32), 512, lds8, stream>>>(batt, WoT, d_out, nullptr, nullptr, 4096, 2048, 2048);
}

// Round 14
// 190.720 us; speedup vs baseline: 1.7292x; 1.0161x over previous
//
#include <hip/hip_runtime.h>
#include <hip/hip_bf16.h>
#include <stdint.h>
#include <math.h>

#define B_ 2
#define S_ 2048
#define H_ 2048
#define NH_ 16
#define NKV_ 4
#define HD_ 128

typedef __bf16 bf16;
typedef __bf16 bf16x8 __attribute__((ext_vector_type(8)));
typedef __bf16 bf16x4 __attribute__((ext_vector_type(4)));
typedef float f32x4 __attribute__((ext_vector_type(4)));

__device__ __forceinline__ void async_copy16(const void* g, void* l) {
  __builtin_amdgcn_global_load_lds(
      (const __attribute__((address_space(1))) void*)(uintptr_t)g,
      (__attribute__((address_space(3))) void*)(uintptr_t)l,
      16, 0, 0);
}

__device__ __forceinline__ f32x4 mfma16(bf16x8 a, bf16x8 b, f32x4 c) {
  return __builtin_amdgcn_mfma_f32_16x16x32_bf16(a, b, c, 0, 0, 0);
}

// ---------------- merged prep kernel ----------------
// bids [0,10240): weight transposes (Wq|Wk|Wv -> WqkvT rows {0,2048,2560}; Wo -> WoT)
// bids [10240,18432): x f32 -> bf16 (4 els/thread)
// bids [18432,18944): RoPE cos/sin table

__global__ void prep_all_k(const float* __restrict__ x,
                           const float* __restrict__ Wq, const float* __restrict__ Wk,
                           const float* __restrict__ Wv, const float* __restrict__ Wo,
                           bf16* __restrict__ xb, bf16* __restrict__ WqkvT,
                           bf16* __restrict__ WoT, float2* __restrict__ tab) {
  __shared__ float tile[32][33];
  const int bid = blockIdx.x;
  const int tid = threadIdx.x;

  if (bid < 10240) {
    const float* W; bf16* Wt; int N, bx, by;
    if (bid < 4096)      { W = Wq; Wt = WqkvT;                       N = 2048; int b2 = bid;        bx = b2 & 63; by = b2 >> 6; }
    else if (bid < 5120) { W = Wk; Wt = WqkvT + (size_t)2048 * 2048; N = 512;  int b2 = bid - 4096; bx = b2 & 15; by = b2 >> 4; }
    else if (bid < 6144) { W = Wv; Wt = WqkvT + (size_t)2560 * 2048; N = 512;  int b2 = bid - 5120; bx = b2 & 15; by = b2 >> 4; }
    else                 { W = Wo; Wt = WoT;                         N = 2048; int b2 = bid - 6144; bx = b2 & 63; by = b2 >> 6; }
    const int K = 2048;
    int n0 = bx * 32, k0 = by * 32;
    int tx = tid & 31, ty = tid >> 5;   // (32, 8)
#pragma unroll
    for (int j = 0; j < 32; j += 8)
      tile[ty + j][tx] = W[(size_t)(k0 + ty + j) * N + n0 + tx];
    __syncthreads();
#pragma unroll
    for (int j = 0; j < 32; j += 8)
      Wt[(size_t)(n0 + ty + j) * K + k0 + tx] = (bf16)tile[tx][ty + j];
  } else if (bid < 18432) {
    int i = ((bid - 10240) * 256 + tid) * 4;
    float4 v = *(const float4*)(x + i);
    bf16x4 r;
    r[0] = (bf16)v.x; r[1] = (bf16)v.y; r[2] = (bf16)v.z; r[3] = (bf16)v.w;
    *(bf16x4*)(xb + i) = r;
  } else {
    int i = (bid - 18432) * 256 + tid;   // S_*64
    int p = i >> 6, d = i & 63;
    float invf = expf(-((float)(2 * d) / 128.0f) * 9.210340371976184f);
    float fr = (float)p * invf;
    float sv, cv;
    sincosf(fr, &sv, &cv);
    tab[i] = make_float2(cv, sv);
  }
}

// vectorized RoPE (K only now): each thread handles 8 (d, d+64) pairs.
__global__ void rope_apply_v8_k(bf16* __restrict__ t, const int* __restrict__ pos_ids,
                                const float2* __restrict__ tab, int hshift, int hmask,
                                float scale) {
  int i = blockIdx.x * 256 + threadIdx.x;
  int g = i & 7;
  int tmp = i >> 3;
  int h = tmp & hmask;
  int row = tmp >> hshift;
  int pos = pos_ids[row];
  size_t base = (((size_t)row << hshift) + h) * HD_ + g * 8;
  const float2* tb = tab + pos * 64 + g * 8;
  bf16x8 lo = *(const bf16x8*)(t + base);
  bf16x8 hi = *(const bf16x8*)(t + base + 64);
  float4 t0 = *(const float4*)(tb);
  float4 t1 = *(const float4*)(tb + 2);
  float4 t2 = *(const float4*)(tb + 4);
  float4 t3 = *(const float4*)(tb + 6);
  float cs[8], sn[8];
  cs[0]=t0.x; sn[0]=t0.y; cs[1]=t0.z; sn[1]=t0.w;
  cs[2]=t1.x; sn[2]=t1.y; cs[3]=t1.z; sn[3]=t1.w;
  cs[4]=t2.x; sn[4]=t2.y; cs[5]=t2.z; sn[5]=t2.w;
  cs[6]=t3.x; sn[6]=t3.y; cs[7]=t3.z; sn[7]=t3.w;
  bf16x8 olo, ohi;
#pragma unroll
  for (int j = 0; j < 8; ++j) {
    float a = (float)lo[j], b = (float)hi[j];
    olo[j] = (bf16)((a * cs[j] - b * sn[j]) * scale);
    ohi[j] = (bf16)((b * cs[j] + a * sn[j]) * scale);
  }
  *(bf16x8*)(t + base) = olo;
  *(bf16x8*)(t + base + 64) = ohi;
}

// ---------------- 256xBN 8-wave GEMM (m201-style) ----------------

template <int MODE, int NJ>
__global__ __launch_bounds__(512) void gemm256_k(const bf16* __restrict__ A,
                                                 const bf16* __restrict__ Bt,
                                                 void* __restrict__ C0,
                                                 void* __restrict__ C1,
                                                 void* __restrict__ C2,
                                                 int M, int N, int K) {
  extern __shared__ __align__(16) char smem[];
  constexpr int BUFSZ = 32768 + NJ * 8192;
  const int tid = threadIdx.x;
  const int lane = tid & 63;
  const int w = tid >> 6;
  const int wm = w >> 2;          // 0..1 (M half)
  const int wn = w & 3;           // 0..3 (N quarter)
  const int g16 = lane >> 4, c16 = lane & 15;
  const int row0 = blockIdx.y * 256;
  const int col0 = blockIdx.x * (NJ * 64);
  const int srow = tid >> 3;
  const int sslot = tid & 7;
  const int ldsw = w * 1024;

  auto stage = [&](int buf, int kt, int r) {
    int rr = (r < 4) ? r : r - 4;
    int row = rr * 64 + srow;
    int ss = sslot ^ (row & 7);
    const bf16* src = (r < 4) ? (A + (size_t)(row0 + row) * K)
                              : (Bt + (size_t)(col0 + row) * K);
    async_copy16(src + (kt << 6) + ss * 8,
                 smem + buf * BUFSZ + ((r < 4) ? 0 : 32768) + rr * 8192 + ldsw);
  };

  int offA[2][8], offB[2][NJ];
#pragma unroll
  for (int ks = 0; ks < 2; ++ks) {
#pragma unroll
    for (int i = 0; i < 8; ++i) {
      int ra = wm * 128 + i * 16 + c16;
      offA[ks][i] = ra * 128 + (((ks * 4 + g16) ^ (ra & 7)) << 4);
    }
#pragma unroll
    for (int j = 0; j < NJ; ++j) {
      int rb = wn * (16 * NJ) + j * 16 + c16;
      offB[ks][j] = 32768 + rb * 128 + (((ks * 4 + g16) ^ (rb & 7)) << 4);
    }
  }

  const f32x4 fz = {0.f, 0.f, 0.f, 0.f};
  f32x4 acc[8][NJ];
#pragma unroll
  for (int i = 0; i < 8; ++i)
#pragma unroll
    for (int j = 0; j < NJ; ++j) acc[i][j] = fz;

  const int nkt = K >> 6;
#pragma unroll
  for (int r = 0; r < 4 + NJ; ++r) stage(0, 0, r);
  asm volatile("s_waitcnt vmcnt(0)" ::: "memory");
  __builtin_amdgcn_s_barrier();

  for (int t = 0; t < nkt; ++t) {
    const char* Ab = smem + (t & 1) * BUFSZ;
    const bool pf = (t + 1 < nkt);
    const int nb = (t + 1) & 1;
    bf16x8 bfr[2][NJ];

    {
      bf16x8 af[2][2];
#pragma unroll
      for (int ks = 0; ks < 2; ++ks) {
#pragma unroll
        for (int j = 0; j < NJ; ++j) bfr[ks][j] = *(const bf16x8*)(Ab + offB[ks][j]);
        af[ks][0] = *(const bf16x8*)(Ab + offA[ks][0]);
        af[ks][1] = *(const bf16x8*)(Ab + offA[ks][1]);
      }
      if (pf) { stage(nb, t + 1, 0); stage(nb, t + 1, 1); stage(nb, t + 1, 2); stage(nb, t + 1, 3); }
      __builtin_amdgcn_s_barrier();
      asm volatile("s_waitcnt lgkmcnt(0)" ::: "memory");
      __builtin_amdgcn_sched_barrier(0);
      __builtin_amdgcn_s_setprio(1);
#pragma unroll
      for (int ks = 0; ks < 2; ++ks)
#pragma unroll
        for (int m = 0; m < 2; ++m)
#pragma unroll
          for (int j = 0; j < NJ; ++j)
            acc[m][j] = mfma16(af[ks][m], bfr[ks][j], acc[m][j]);
      __builtin_amdgcn_s_setprio(0);
      __builtin_amdgcn_sched_barrier(0);
      __builtin_amdgcn_s_barrier();
    }

#pragma unroll
    for (int q = 1; q < 4; ++q) {
      bf16x8 af[2][2];
#pragma unroll
      for (int ks = 0; ks < 2; ++ks) {
        af[ks][0] = *(const bf16x8*)(Ab + offA[ks][q * 2]);
        af[ks][1] = *(const bf16x8*)(Ab + offA[ks][q * 2 + 1]);
      }
      if (q == 1 && pf) {
#pragma unroll
        for (int r = 0; r < NJ; ++r) stage(nb, t + 1, 4 + r);
      }
      __builtin_amdgcn_s_barrier();
      asm volatile("s_waitcnt lgkmcnt(0)" ::: "memory");
      __builtin_amdgcn_sched_barrier(0);
      __builtin_amdgcn_s_setprio(1);
#pragma unroll
      for (int ks = 0; ks < 2; ++ks)
#pragma unroll
        for (int m = 0; m < 2; ++m)
#pragma unroll
          for (int j = 0; j < NJ; ++j)
            acc[q * 2 + m][j] = mfma16(af[ks][m], bfr[ks][j], acc[q * 2 + m][j]);
      __builtin_amdgcn_s_setprio(0);
      __builtin_amdgcn_sched_barrier(0);
      if (q == 3 && pf) asm volatile("s_waitcnt vmcnt(0)" ::: "memory");
      __builtin_amdgcn_s_barrier();
    }
  }

#pragma unroll
  for (int i = 0; i < 8; ++i) {
    int gr0 = row0 + wm * 128 + i * 16 + g16 * 4;
#pragma unroll
    for (int j = 0; j < NJ; ++j) {
      int gc = col0 + wn * (16 * NJ) + j * 16 + c16;
      if constexpr (MODE == 2) {
        if (gc < 2048) {
#pragma unroll
          for (int r = 0; r < 4; ++r)
            ((bf16*)C0)[(size_t)(gr0 + r) * 2048 + gc] = (bf16)acc[i][j][r];
        } else if (gc < 2560) {
#pragma unroll
          for (int r = 0; r < 4; ++r)
            ((bf16*)C1)[(size_t)(gr0 + r) * 512 + (gc - 2048)] = (bf16)acc[i][j][r];
        } else {
          int dv = gc - 2560;
          int hkv = dv >> 7, d = dv & 127;
          size_t va = (((size_t)(gr0 >> 11) * NKV_ + hkv) * HD_ + d) * S_ + (gr0 & 2047);
          bf16x4 pk;
#pragma unroll
          for (int r = 0; r < 4; ++r) pk[r] = (bf16)acc[i][j][r];
          *(bf16x4*)((bf16*)C2 + va) = pk;
        }
      } else {
#pragma unroll
        for (int r = 0; r < 4; ++r) {
          if constexpr (MODE == 1)
            ((float*)C0)[(size_t)(gr0 + r) * N + gc] = acc[i][j][r];
          else
            ((bf16*)C0)[(size_t)(gr0 + r) * N + gc] = (bf16)acc[i][j][r];
        }
      }
    }
  }
}

// ---------------- 128x256 8-wave pipelined GEMM (O-proj: 256 blocks exact) ----------------

template <int MODE>
__global__ __launch_bounds__(512) void gemm8_k(const bf16* __restrict__ A,
                                               const bf16* __restrict__ Bt,
                                               void* __restrict__ C0,
                                               void* __restrict__ C1,
                                               void* __restrict__ C2,
                                               int M, int N, int K) {
  extern __shared__ __align__(16) char smem[];
  const int tid = threadIdx.x;
  const int lane = tid & 63;
  const int w = tid >> 6;
  const int wm = w >> 2;
  const int wn = w & 3;
  const int g16 = lane >> 4, c16 = lane & 15;
  const int row0 = blockIdx.y * 128;
  const int col0 = blockIdx.x * 256;
  const int srow = tid >> 3;
  const int sslot = tid & 7;
  const int ldsw = w * 1024;

  auto stageA = [&](int s, int kt, int r) {
    int row = r * 64 + srow;
    int ss = sslot ^ (row & 7);
    async_copy16(A + (size_t)(row0 + row) * K + (kt << 6) + ss * 8,
                 smem + s * 49152 + r * 8192 + ldsw);
  };
  auto stageB = [&](int s, int kt, int r) {
    int row = r * 64 + srow;
    int ss = sslot ^ (row & 7);
    async_copy16(Bt + (size_t)(col0 + row) * K + (kt << 6) + ss * 8,
                 smem + s * 49152 + 16384 + r * 8192 + ldsw);
  };

  int offA[2][4], offB[2][4];
#pragma unroll
  for (int ks = 0; ks < 2; ++ks) {
#pragma unroll
    for (int i = 0; i < 4; ++i) {
      int ra = wm * 64 + i * 16 + c16;
      offA[ks][i] = ra * 128 + (((ks * 4 + g16) ^ (ra & 7)) << 4);
      int rb = wn * 64 + i * 16 + c16;
      offB[ks][i] = rb * 128 + (((ks * 4 + g16) ^ (rb & 7)) << 4);
    }
  }

  const f32x4 fz = {0.f, 0.f, 0.f, 0.f};
  f32x4 acc[4][4];
#pragma unroll
  for (int i = 0; i < 4; ++i)
#pragma unroll
    for (int j = 0; j < 4; ++j) acc[i][j] = fz;

  const int nkt = K >> 6;
#pragma unroll
  for (int r = 0; r < 2; ++r) stageA(0, 0, r);
#pragma unroll
  for (int r = 0; r < 4; ++r) stageB(0, 0, r);
#pragma unroll
  for (int r = 0; r < 2; ++r) stageA(1, 1, r);
#pragma unroll
  for (int r = 0; r < 4; ++r) stageB(1, 1, r);
  asm volatile("s_waitcnt vmcnt(6)" ::: "memory");
  __builtin_amdgcn_s_barrier();

  int ct = 0, pt = 2;
  for (int t = 0; t < nkt; ++t) {
    const char* Ab = smem + ct * 49152;
    const char* Bb = Ab + 16384;
    const bool pf = (t + 2 < nkt);
    const int kpf = t + 2;
    bf16x8 af[4], bfr[4];

#pragma unroll
    for (int i = 0; i < 4; ++i) af[i] = *(const bf16x8*)(Ab + offA[0][i]);
#pragma unroll
    for (int j = 0; j < 4; ++j) bfr[j] = *(const bf16x8*)(Bb + offB[0][j]);
    if (pf) { stageA(pt, kpf, 0); stageA(pt, kpf, 1); stageB(pt, kpf, 0); }
    __builtin_amdgcn_s_barrier();
    asm volatile("s_waitcnt lgkmcnt(0)" ::: "memory");
    __builtin_amdgcn_sched_barrier(0);
    __builtin_amdgcn_s_setprio(1);
#pragma unroll
    for (int i = 0; i < 4; ++i)
#pragma unroll
      for (int j = 0; j < 4; ++j) acc[i][j] = mfma16(af[i], bfr[j], acc[i][j]);
    __builtin_amdgcn_s_setprio(0);
    __builtin_amdgcn_sched_barrier(0);
    __builtin_amdgcn_s_barrier();

#pragma unroll
    for (int i = 0; i < 4; ++i) af[i] = *(const bf16x8*)(Ab + offA[1][i]);
#pragma unroll
    for (int j = 0; j < 4; ++j) bfr[j] = *(const bf16x8*)(Bb + offB[1][j]);
    if (pf) { stageB(pt, kpf, 1); stageB(pt, kpf, 2); stageB(pt, kpf, 3); }
    if (pf) asm volatile("s_waitcnt vmcnt(6)" ::: "memory");
    else    asm volatile("s_waitcnt vmcnt(0)" ::: "memory");
    __builtin_amdgcn_s_barrier();
    asm volatile("s_waitcnt lgkmcnt(0)" ::: "memory");
    __builtin_amdgcn_sched_barrier(0);
    __builtin_amdgcn_s_setprio(1);
#pragma unroll
    for (int i = 0; i < 4; ++i)
#pragma unroll
      for (int j = 0; j < 4; ++j) acc[i][j] = mfma16(af[i], bfr[j], acc[i][j]);
    __builtin_amdgcn_s_setprio(0);
    __builtin_amdgcn_sched_barrier(0);
    __builtin_amdgcn_s_barrier();

    ct = (ct == 2) ? 0 : ct + 1;
    pt = (pt == 2) ? 0 : pt + 1;
  }

#pragma unroll
  for (int i = 0; i < 4; ++i) {
    int gr0 = row0 + wm * 64 + i * 16 + g16 * 4;
#pragma unroll
    for (int j = 0; j < 4; ++j) {
      int gc = col0 + wn * 64 + j * 16 + c16;
#pragma unroll
      for (int r = 0; r < 4; ++r) {
        if constexpr (MODE == 1)
          ((float*)C0)[(size_t)(gr0 + r) * N + gc] = acc[i][j][r];
        else
          ((bf16*)C0)[(size_t)(gr0 + r) * N + gc] = (bf16)acc[i][j][r];
      }
    }
  }
}

// ---------------- flash attention (causal, GQA) — r13 structure + fused Q-RoPE ----------------
// Q-RoPE applied in-register in the prologue: pair (d, d+64) = chunks (ksq, ksq+2)
// of the same thread's qf. Saves the 64MB Q-rope global pass + one launch.

__global__ __launch_bounds__(256, 2) void attn_fwd_k(const bf16* __restrict__ Qg,
                                                     const bf16* __restrict__ Kg,
                                                     const bf16* __restrict__ VTg,
                                                     const int* __restrict__ pos_ids,
                                                     const float2* __restrict__ tab,
                                                     bf16* __restrict__ Og) {
  __shared__ __align__(16) bf16 Ks[2][64 * 128];
  __shared__ __align__(16) bf16 Vt[2][128 * 64];

  const int tid = threadIdx.x;
  const int lane = tid & 63;
  const int w = tid >> 6;
  const int g16 = lane >> 4;
  const int c16 = lane & 15;

  const int bid = blockIdx.x;
  const int i_ = ((bid >> 8) << 7) | ((bid & 255) >> 1);
  const int par = ((bid & 1) ^ (bid >> 8)) & 1;
  const int qb = par ? (i_ >> 5) : (15 - (i_ >> 5));
  const int bh = i_ & 31;
  const int b = bh >> 4;
  const int h = bh & 15;
  const int hkv = h >> 2;
  const int q0 = qb * 128;
  const int qw = q0 + w * 32;

  bf16x8 qf[2][4];
#pragma unroll
  for (int nq = 0; nq < 2; ++nq)
#pragma unroll
    for (int ksq = 0; ksq < 4; ++ksq)
      qf[nq][ksq] = *(const bf16x8*)(Qg + ((size_t)(b * S_ + qw + nq * 16 + c16) * NH_ + h) * HD_ + (ksq * 4 + g16) * 8);

  // ---- fused Q-RoPE (scale log2e/sqrt(HD) folded): lo=qf[ksq], hi=qf[ksq+2] ----
#pragma unroll
  for (int nq = 0; nq < 2; ++nq) {
    int grow = b * S_ + qw + nq * 16 + c16;
    int pos = pos_ids[grow];
    const float2* tb0 = tab + pos * 64;
#pragma unroll
    for (int ksq = 0; ksq < 2; ++ksq) {
      const float2* tb = tb0 + (ksq * 4 + g16) * 8;
      float4 t0 = *(const float4*)(tb);
      float4 t1 = *(const float4*)(tb + 2);
      float4 t2 = *(const float4*)(tb + 4);
      float4 t3 = *(const float4*)(tb + 6);
      float cs[8], sn[8];
      cs[0]=t0.x; sn[0]=t0.y; cs[1]=t0.z; sn[1]=t0.w;
      cs[2]=t1.x; sn[2]=t1.y; cs[3]=t1.z; sn[3]=t1.w;
      cs[4]=t2.x; sn[4]=t2.y; cs[5]=t2.z; sn[5]=t2.w;
      cs[6]=t3.x; sn[6]=t3.y; cs[7]=t3.z; sn[7]=t3.w;
      bf16x8 lo = qf[nq][ksq], hi = qf[nq][ksq + 2];
#pragma unroll
      for (int j = 0; j < 8; ++j) {
        float a = (float)lo[j], bb = (float)hi[j];
        lo[j] = (bf16)((a * cs[j] - bb * sn[j]) * 0.12753102f);
        hi[j] = (bf16)((bb * cs[j] + a * sn[j]) * 0.12753102f);
      }
      qf[nq][ksq] = lo;
      qf[nq][ksq + 2] = hi;
    }
  }

  float m_run[2] = {-1e30f, -1e30f};
  float l_run[2] = {0.f, 0.f};
  const f32x4 fz = {0.f, 0.f, 0.f, 0.f};
  f32x4 acc[2][8];
#pragma unroll
  for (int nq = 0; nq < 2; ++nq)
#pragma unroll
    for (int dt = 0; dt < 8; ++dt) acc[nq][dt] = fz;

  const size_t kbase = ((size_t)b * S_ * NKV_ + hkv) * HD_;
  const size_t vbase = ((size_t)(b * NKV_ + hkv)) * HD_ * S_;

  auto stage = [&](int buf, int kv0) {
#pragma unroll
    for (int rd = 0; rd < 4; ++rd) {
      int Lb = rd * 256 + w * 64;
      int row = (Lb + lane) >> 4;
      int ssl = (lane & 15) ^ (row & 7);
      async_copy16(Kg + kbase + (size_t)(kv0 + row) * (NKV_ * HD_) + ssl * 8,
                   (char*)&Ks[buf][0] + Lb * 16);
    }
#pragma unroll
    for (int rd = 0; rd < 4; ++rd) {
      int Lb = rd * 256 + w * 64;
      int row = (Lb + lane) >> 3;
      int ssl = (lane & 7) ^ (row & 7);
      async_copy16(VTg + vbase + (size_t)row * S_ + kv0 + ssl * 8,
                   (char*)&Vt[buf][0] + Lb * 16);
    }
  };

  const int ntiles = 2 * qb + 2;
  stage(0, 0);
  int cur = 0;

  for (int t = 0; t < ntiles; ++t) {
    __syncthreads();
    if (t + 1 < ntiles) stage(cur ^ 1, (t + 1) * 64);
    const int kv0 = t * 64;

    if (kv0 <= qw + 31) {
      const bf16* KsC = &Ks[cur][0];
      const bf16* VtC = &Vt[cur][0];

      f32x4 sc[2][4];
#pragma unroll
      for (int nq = 0; nq < 2; ++nq)
#pragma unroll
        for (int mt = 0; mt < 4; ++mt) sc[nq][mt] = fz;

      __builtin_amdgcn_s_setprio(1);
#pragma unroll
      for (int ksq = 0; ksq < 4; ++ksq) {
        bf16x8 kf[4];
#pragma unroll
        for (int mt = 0; mt < 4; ++mt) {
          int gp = c16 >> 2, rp = c16 & 3;
          int blk = 8 * (mt >> 1) + 2 * gp + ((mt & 1) ^ (gp & 1));
          int row = blk * 4 + rp;
          kf[mt] = *(const bf16x8*)((const char*)KsC + row * 256 + (((ksq * 4 + g16) ^ (row & 7)) << 4));
        }
#pragma unroll
        for (int nq = 0; nq < 2; ++nq)
#pragma unroll
          for (int mt = 0; mt < 4; ++mt)
            sc[nq][mt] = mfma16(kf[mt], qf[nq][ksq], sc[nq][mt]);
      }
      __builtin_amdgcn_s_setprio(0);

      if (kv0 + 63 > qw) {
#pragma unroll
        for (int nq = 0; nq < 2; ++nq) {
          int qa = qw + nq * 16 + c16;
#pragma unroll
          for (int mt = 0; mt < 4; ++mt) {
            int blk = 8 * (mt >> 1) + 2 * g16 + ((mt & 1) ^ (g16 & 1));
#pragma unroll
            for (int r = 0; r < 4; ++r) {
              int ka = kv0 + blk * 4 + r;
              if (ka > qa) sc[nq][mt][r] = -1e30f;
            }
          }
        }
      }

      float mx[2];
#pragma unroll
      for (int nq = 0; nq < 2; ++nq) {
        float v = sc[nq][0][0];
#pragma unroll
        for (int mt = 0; mt < 4; ++mt)
#pragma unroll
          for (int r = 0; r < 4; ++r) v = fmaxf(v, sc[nq][mt][r]);
        v = fmaxf(v, __shfl_xor(v, 16));
        v = fmaxf(v, __shfl_xor(v, 32));
        mx[nq] = v;
      }
      if (__any((mx[0] > m_run[0] + 8.f) || (mx[1] > m_run[1] + 8.f))) {
#pragma unroll
        for (int nq = 0; nq < 2; ++nq) {
          float mn = fmaxf(m_run[nq], mx[nq]);
          float corr = exp2f(m_run[nq] - mn);
          m_run[nq] = mn;
          l_run[nq] *= corr;
#pragma unroll
          for (int dt = 0; dt < 8; ++dt) acc[nq][dt] *= corr;
        }
      }
#pragma unroll
      for (int nq = 0; nq < 2; ++nq) {
        float sum = 0.f;
#pragma unroll
        for (int mt = 0; mt < 4; ++mt)
#pragma unroll
          for (int r = 0; r < 4; ++r) {
            float p = exp2f(sc[nq][mt][r] - m_run[nq]);
            sc[nq][mt][r] = p;
            sum += p;
          }
        sum += __shfl_xor(sum, 16);
        sum += __shfl_xor(sum, 32);
        l_run[nq] += sum;
      }

      bf16x8 pa[2][2];
#pragma unroll
      for (int nq = 0; nq < 2; ++nq)
#pragma unroll
        for (int ks = 0; ks < 2; ++ks) {
          f32x4 sA = (g16 & 1) ? sc[nq][2 * ks + 1] : sc[nq][2 * ks];
          f32x4 sB = (g16 & 1) ? sc[nq][2 * ks] : sc[nq][2 * ks + 1];
          bf16x8 tf;
          tf[0] = (bf16)sA[0]; tf[1] = (bf16)sA[1]; tf[2] = (bf16)sA[2]; tf[3] = (bf16)sA[3];
          tf[4] = (bf16)sB[0]; tf[5] = (bf16)sB[1]; tf[6] = (bf16)sB[2]; tf[7] = (bf16)sB[3];
          pa[nq][ks] = tf;
        }

      __builtin_amdgcn_s_setprio(1);
#pragma unroll
      for (int ks = 0; ks < 2; ++ks)
#pragma unroll
        for (int dt = 0; dt < 8; ++dt) {
          int rv = dt * 16 + c16;
          bf16x8 vf = *(const bf16x8*)((const char*)VtC + rv * 128 + (((ks * 4 + g16) ^ (rv & 7)) << 4));
          acc[0][dt] = mfma16(vf, pa[0][ks], acc[0][dt]);
          acc[1][dt] = mfma16(vf, pa[1][ks], acc[1][dt]);
        }
      __builtin_amdgcn_s_setprio(0);
    }
    cur ^= 1;
  }

#pragma unroll
  for (int nq = 0; nq < 2; ++nq) {
    float inv = 1.0f / l_run[nq];
    size_t base = ((size_t)(b * S_ + qw + nq * 16 + c16) * NH_ + h) * HD_ + g16 * 4;
#pragma unroll
    for (int dt = 0; dt < 8; ++dt) {
      bf16x4 ov;
#pragma unroll
      for (int r = 0; r < 4; ++r) ov[r] = (bf16)(acc[nq][dt][r] * inv);
      *(bf16x4*)(Og + base + dt * 16) = ov;
    }
  }
}

// ---------------- launcher ----------------

extern "C" void kernel_launch(void* const* d_in, const int* in_sizes, int n_in,
                              void* d_out, int out_size, void* d_ws, size_t ws_size,
                              hipStream_t stream) {
  const float* x  = (const float*)d_in[0];
  const int* pos  = (const int*)d_in[2];
  const float* Wq = (const float*)d_in[3];
  const float* Wk = (const float*)d_in[4];
  const float* Wv = (const float*)d_in[5];
  const float* Wo = (const float*)d_in[6];

  char* ws = (char*)d_ws;
  size_t off = 0;
  auto alloc = [&](size_t bytes) -> char* {
    char* p = ws + off;
    off += (bytes + 255) & ~(size_t)255;
    return p;
  };
  const size_t rows = (size_t)B_ * S_;
  bf16* xb    = (bf16*)alloc(rows * H_ * 2);
  bf16* bq    = (bf16*)alloc(rows * (NH_ * HD_) * 2);
  bf16* batt  = (bf16*)alloc(rows * (NH_ * HD_) * 2);
  bf16* WqkvT = (bf16*)alloc((size_t)3072 * H_ * 2);   // rows: Wq 0..2047 | Wk ..2559 | Wv ..3071
  bf16* WoT   = (bf16*)alloc((size_t)H_ * H_ * 2);
  bf16* bk    = (bf16*)alloc(rows * (NKV_ * HD_) * 2);
  bf16* VT    = (bf16*)alloc(rows * (NKV_ * HD_) * 2); // [b][hkv][d][S]
  float2* tab = (float2*)alloc((size_t)S_ * 64 * sizeof(float2));

  auto* fqkv = gemm256_k<2, 3>;
  auto* fo   = gemm8_k<1>;
  const int lds256 = 2 * (32768 + 3 * 8192);  // 114688
  const int lds8   = 3 * 49152;               // 147456
  (void)hipFuncSetAttribute((const void*)fqkv, hipFuncAttributeMaxDynamicSharedMemorySize, lds256);
  (void)hipFuncSetAttribute((const void*)fo, hipFuncAttributeMaxDynamicSharedMemorySize, lds8);

  // merged prep: transposes + x convert + rope table in one launch
  prep_all_k<<<18944, 256, 0, stream>>>(x, Wq, Wk, Wv, Wo, xb, WqkvT, WoT, tab);

  // fused QKV projection: 256x192 tiles, grid 16x16 = 256 blocks exact
  gemm256_k<2, 3><<<dim3(16, 16), 512, lds256, stream>>>(xb, WqkvT, bq, bk, VT, 4096, 3072, 2048);

  // RoPE: K only (Q-RoPE fused into attention prologue)
  rope_apply_v8_k<<<(4096 * NKV_ * 8) / 256, 256, 0, stream>>>(bk, pos, tab, 2, 3, 1.0f);

  // attention: 512 blocks, parity-paired heavy/light, fused Q-RoPE
  attn_fwd_k<<<dim3(512), 256, 0, stream>>>(bq, bk, VT, pos, tab, batt);

  // output projection (f32 out): 128x256 tile, 8x32 = 256 blocks exact fit
  gemm8_k<1><<<dim3(8, 32), 512, lds8, stream>>>(batt, WoT, d_out, nullptr, nullptr, 4096, 2048, 2048);
}